// Round 10
// baseline (486.696 us; speedup 1.0000x reference)
//
#include <hip/hip_runtime.h>
#include <hip/hip_bf16.h>
#include <hip/hip_cooperative_groups.h>

// GATNet: 2x GATConv + 2-layer MLP.
// R9 -> R10: de-risked hybrid. R9's full mega-fusion failed because build_coop
// (grid = occ*256 = 2048) almost certainly hit the cooperative co-residency
// limit and never launched (output matched the "poisoned CSR -> zero edges"
// signature). Now: the 5 proven R8 main kernels stay unchanged; ONLY the CSR/
// prep chain (5 dispatches) is fused into one cooperative kernel with a FIXED
// 512-block grid (2 blocks/CU guaranteed co-resident: 8KB LDS, VGPR<=256 via
// __launch_bounds__(256,2)). Attribute check + launch-rc check fall back to
// the R8 5-kernel chain (both branches call-invariant -> graph-safe).

namespace cg = cooperative_groups;

__device__ __forceinline__ float lrelu(float x){ return x > 0.f ? x : 0.2f*x; }
__device__ __forceinline__ float elu_f(float x){ return x > 0.f ? x : __expf(x) - 1.f; }
__device__ __forceinline__ unsigned short f2bf(float f){
  __hip_bfloat16 h = __float2bfloat16(f);   // RNE
  return *reinterpret_cast<unsigned short*>(&h);
}
__device__ __forceinline__ float bflo(unsigned int u){ return __uint_as_float(u << 16); }
__device__ __forceinline__ float bfhi(unsigned int u){ return __uint_as_float(u & 0xffff0000u); }
__device__ __forceinline__ unsigned int packbf(float a, float b){
  return (unsigned int)f2bf(a) | ((unsigned int)f2bf(b) << 16);
}

typedef __attribute__((ext_vector_type(8))) short bf16x8;
typedef __attribute__((ext_vector_type(4))) float f32x4;

// ================= cooperative CSR/prep build (one dispatch) =================
__global__ __launch_bounds__(256, 2) void build_coop(
    const float* __restrict__ x, unsigned short* __restrict__ xb, int N,
    const float* __restrict__ W1, unsigned short* __restrict__ BT1a, unsigned short* __restrict__ BT1b,
    const float* __restrict__ W2, unsigned short* __restrict__ BT2,
    const float* __restrict__ Wm1, unsigned short* __restrict__ BT3,
    const float* __restrict__ a1s, const float* __restrict__ a1d, float* __restrict__ va,
    float* __restrict__ as1, float* __restrict__ ad1,
    const int* __restrict__ srcp, const int* __restrict__ dstp, int E,
    int* __restrict__ bcount, int* __restrict__ boff, int* __restrict__ gcur,
    unsigned int* __restrict__ pairs, int* __restrict__ rowptr, int* __restrict__ csr, int NB)
{
  cg::grid_group g = cg::this_grid();
  __shared__ int h[1024];
  __shared__ int rb[1024];
  const int t = threadIdx.x;
  const int stride = gridDim.x*256;

  // ---- phase 0: weight transposes + va + zero bucket arrays ----
  const int S1 = 128*128, S2 = 128*256, S3 = 128*128;
  const int prepTotal = S1 + S2 + S3 + 512 + 2048;
  for (int idx = blockIdx.x*256 + t; idx < prepTotal; idx += stride){
    if (idx < S1){
      int n = idx >> 7, k = idx & 127;
      BT1a[idx] = f2bf(W1[(size_t)k*256 + n]);
      BT1b[idx] = f2bf(W1[(size_t)k*256 + 128 + n]);
    } else if (idx < S1 + S2){
      int j = idx - S1;
      int n = j >> 8, k = j & 255;
      BT2[j] = f2bf(W2[(size_t)k*128 + n]);
    } else if (idx < S1 + S2 + S3){
      int j = idx - S1 - S2;
      int n = j >> 7, k = j & 127;
      BT3[j] = f2bf(Wm1[(size_t)k*128 + n]);
    } else if (idx < S1 + S2 + S3 + 512){
      int j = idx - S1 - S2 - S3;
      int v = j >> 7, k = j & 127;
      const float* avec = (v < 2) ? a1s : a1d;
      int head = v & 1;
      const float* wrow = W1 + (size_t)k*256 + head*128;
      const float* arow = avec + head*128;
      float s = 0.f;
      #pragma unroll 8
      for (int f = 0; f < 128; ++f) s += wrow[f]*arow[f];
      va[j] = s;
    } else {
      int z = idx - (S1 + S2 + S3 + 512);
      if (z < 1024){ if (z < NB) bcount[z] = 0; }
      else { z -= 1024; if (z < NB) gcur[z] = 0; }
    }
  }
  g.sync();

  // ---- phase A: x->bf16 + conv1 alpha dots; then edge histogram ----
  const int total = N*32;
  for (int i = blockIdx.x*256 + t; i < total; i += stride){
    float4 v = ((const float4*)x)[i];
    ushort4 u; u.x=f2bf(v.x); u.y=f2bf(v.y); u.z=f2bf(v.z); u.w=f2bf(v.w);
    ((ushort4*)xb)[i] = u;
    int c = (i & 31) << 2;
    float4 vs0 = *(const float4*)(va + c);
    float4 vs1 = *(const float4*)(va + 128 + c);
    float4 vd0 = *(const float4*)(va + 256 + c);
    float4 vd1 = *(const float4*)(va + 384 + c);
    float s0 = v.x*vs0.x + v.y*vs0.y + v.z*vs0.z + v.w*vs0.w;
    float s1 = v.x*vs1.x + v.y*vs1.y + v.z*vs1.z + v.w*vs1.w;
    float d0 = v.x*vd0.x + v.y*vd0.y + v.z*vd0.z + v.w*vd0.w;
    float d1 = v.x*vd1.x + v.y*vd1.y + v.z*vd1.z + v.w*vd1.w;
    #pragma unroll
    for (int m = 1; m <= 16; m <<= 1){
      s0 += __shfl_xor(s0, m); s1 += __shfl_xor(s1, m);
      d0 += __shfl_xor(d0, m); d1 += __shfl_xor(d1, m);
    }
    if ((i & 31) == 0){
      int n = i >> 5;
      *(float2*)(as1 + 2*n) = make_float2(s0, s1);
      *(float2*)(ad1 + 2*n) = make_float2(d0, d1);
    }
  }
  for (int i = t; i < NB; i += 256) h[i] = 0;
  __syncthreads();
  for (int e = blockIdx.x*256 + t; e < E; e += stride)
    atomicAdd(&h[dstp[e] >> 6], 1);
  __syncthreads();
  for (int i = t; i < NB; i += 256)
    if (h[i]) atomicAdd(&bcount[i], h[i]);
  g.sync();

  // ---- phase B: exclusive scan of bucket counts (block 0) ----
  if (blockIdx.x == 0){
    const int lane = t & 63, w = t >> 6;
    int carry = 0;
    for (int base = 0; base < NB; base += 256){
      int idx = base + t;
      int v = (idx < NB) ? bcount[idx] : 0;
      int s = v;
      #pragma unroll
      for (int d = 1; d < 64; d <<= 1){
        int y = __shfl_up(s, d);
        if (lane >= d) s += y;
      }
      if (lane == 63) rb[w] = s;
      __syncthreads();
      int add = 0;
      #pragma unroll
      for (int k = 0; k < 4; ++k) if (k < w) add += rb[k];
      int ctot = rb[0] + rb[1] + rb[2] + rb[3];
      if (idx < NB) boff[idx] = carry + s + add - v;
      carry += ctot;
      __syncthreads();
    }
    if (t == 0) boff[NB] = carry;
  }
  g.sync();

  // ---- phase C: LDS-aggregated scatter into contiguous bucket regions ----
  const int nchunks = (E + 4095)/4096;
  for (int vb = blockIdx.x; vb < nchunks; vb += gridDim.x){
    const int e0 = vb*4096;
    for (int i = t; i < NB; i += 256) h[i] = 0;
    __syncthreads();
    int myb[16]; unsigned int myw[16];
    #pragma unroll
    for (int q = 0; q < 16; ++q){
      int e = e0 + q*256 + t;
      int b = -1; unsigned int w = 0;
      if (e < E){
        int d = dstp[e];
        b = d >> 6;
        w = ((unsigned int)(d & 63) << 26) | (unsigned int)srcp[e];
        atomicAdd(&h[b], 1);
      }
      myb[q] = b; myw[q] = w;
    }
    __syncthreads();
    for (int i = t; i < NB; i += 256)
      rb[i] = h[i] ? atomicAdd(&gcur[i], h[i]) : 0;
    __syncthreads();
    for (int i = t; i < NB; i += 256) h[i] = 0;
    __syncthreads();
    #pragma unroll
    for (int q = 0; q < 16; ++q){
      if (myb[q] >= 0){
        int off = atomicAdd(&h[myb[q]], 1);
        pairs[(size_t)boff[myb[q]] + rb[myb[q]] + off] = myw[q];
      }
    }
    __syncthreads();
  }
  g.sync();

  // ---- phase D: per-bucket CSR build (self loop in slot 0) ----
  for (int vb = blockIdx.x; vb < NB; vb += gridDim.x){
    int* deg  = h;
    int* offs = rb;
    int* cur  = rb + 64;
    const int n0 = vb << 6;
    const int nNodes = min(64, N - n0);
    const int p0 = boff[vb], p1 = boff[vb+1];
    const int base = p0 + n0;
    if (t < 64) deg[t] = (t < nNodes) ? 1 : 0;
    __syncthreads();
    for (int i = p0 + t; i < p1; i += 256)
      atomicAdd(&deg[pairs[i] >> 26], 1);
    __syncthreads();
    if (t < 64){
      int xsc = deg[t];
      #pragma unroll
      for (int d = 1; d < 64; d <<= 1){
        int y = __shfl_up(xsc, d);
        if (t >= d) xsc += y;
      }
      offs[t] = xsc - deg[t];
      cur[t] = 1;
      if (t < nNodes){
        rowptr[n0 + t + 1] = base + xsc;
        csr[base + xsc - deg[t]] = n0 + t;
      }
      if (vb == 0 && t == 0) rowptr[0] = 0;
    }
    __syncthreads();
    for (int i = p0 + t; i < p1; i += 256){
      unsigned int w = pairs[i];
      int dl = w >> 26;
      int s  = (int)(w & 0x03ffffffu);
      int off = atomicAdd(&cur[dl], 1);
      csr[base + offs[dl] + off] = s;
    }
    __syncthreads();
  }
}

// ================= fallback (R8) prep + CSR kernels =================
__global__ void prep_kernel(const float* __restrict__ W1, unsigned short* __restrict__ BT1a,
                            unsigned short* __restrict__ BT1b,
                            const float* __restrict__ W2, unsigned short* __restrict__ BT2,
                            const float* __restrict__ Wm1, unsigned short* __restrict__ BT3,
                            const float* __restrict__ a1s, const float* __restrict__ a1d,
                            float* __restrict__ va, int* __restrict__ bcount,
                            int* __restrict__ gcur, int NB){
  int idx = blockIdx.x*256 + threadIdx.x;
  const int S1 = 128*128, S2 = 128*256, S3 = 128*128;
  if (idx < S1){
    int n = idx >> 7, k = idx & 127;
    BT1a[idx] = f2bf(W1[(size_t)k*256 + n]);
    BT1b[idx] = f2bf(W1[(size_t)k*256 + 128 + n]);
  } else if (idx < S1 + S2){
    int j = idx - S1;
    int n = j >> 8, k = j & 255;
    BT2[j] = f2bf(W2[(size_t)k*128 + n]);
  } else if (idx < S1 + S2 + S3){
    int j = idx - S1 - S2;
    int n = j >> 7, k = j & 127;
    BT3[j] = f2bf(Wm1[(size_t)k*128 + n]);
  } else if (idx < S1 + S2 + S3 + 512){
    int j = idx - S1 - S2 - S3;
    int v = j >> 7, k = j & 127;
    const float* avec = (v < 2) ? a1s : a1d;
    int head = v & 1;
    const float* wrow = W1 + (size_t)k*256 + head*128;
    const float* arow = avec + head*128;
    float s = 0.f;
    #pragma unroll 8
    for (int f = 0; f < 128; ++f) s += wrow[f]*arow[f];
    va[j] = s;
  } else if (idx < S1 + S2 + S3 + 512 + 2048){
    int z = idx - (S1 + S2 + S3 + 512);
    if (z < 1024){ if (z < NB) bcount[z] = 0; }
    else { z -= 1024; if (z < NB) gcur[z] = 0; }
  }
}

__global__ __launch_bounds__(256) void f2bf_hist_kernel(
    const float* __restrict__ x, unsigned short* __restrict__ xb, int N,
    const float* __restrict__ va, float* __restrict__ as1, float* __restrict__ ad1,
    const int* __restrict__ dst, int E, int* __restrict__ bcount, int NB, int nbConv)
{
  __shared__ int h[1024];
  if ((int)blockIdx.x < nbConv){
    int i = blockIdx.x*256 + threadIdx.x;
    int total = N*32;
    float4 v = make_float4(0.f,0.f,0.f,0.f);
    if (i < total){
      v = ((const float4*)x)[i];
      ushort4 u; u.x=f2bf(v.x); u.y=f2bf(v.y); u.z=f2bf(v.z); u.w=f2bf(v.w);
      ((ushort4*)xb)[i] = u;
    }
    int c = (i & 31) << 2;
    float4 vs0 = *(const float4*)(va + c);
    float4 vs1 = *(const float4*)(va + 128 + c);
    float4 vd0 = *(const float4*)(va + 256 + c);
    float4 vd1 = *(const float4*)(va + 384 + c);
    float s0 = v.x*vs0.x + v.y*vs0.y + v.z*vs0.z + v.w*vs0.w;
    float s1 = v.x*vs1.x + v.y*vs1.y + v.z*vs1.z + v.w*vs1.w;
    float d0 = v.x*vd0.x + v.y*vd0.y + v.z*vd0.z + v.w*vd0.w;
    float d1 = v.x*vd1.x + v.y*vd1.y + v.z*vd1.z + v.w*vd1.w;
    #pragma unroll
    for (int m = 1; m <= 16; m <<= 1){
      s0 += __shfl_xor(s0, m); s1 += __shfl_xor(s1, m);
      d0 += __shfl_xor(d0, m); d1 += __shfl_xor(d1, m);
    }
    if ((i & 31) == 0 && i < total){
      int n = i >> 5;
      *(float2*)(as1 + 2*n) = make_float2(s0, s1);
      *(float2*)(ad1 + 2*n) = make_float2(d0, d1);
    }
  } else {
    for (int i = threadIdx.x; i < NB; i += 256) h[i] = 0;
    __syncthreads();
    int b0 = blockIdx.x - nbConv;
    for (int e = b0*256 + threadIdx.x; e < E; e += 64*256)
      atomicAdd(&h[dst[e] >> 6], 1);
    __syncthreads();
    for (int i = threadIdx.x; i < NB; i += 256)
      if (h[i]) atomicAdd(&bcount[i], h[i]);
  }
}

__global__ __launch_bounds__(1024) void bscan_kernel(const int* __restrict__ bcount,
                                                     int* __restrict__ boff, int NB){
  __shared__ int s[1024];
  int t = threadIdx.x;
  int mine = (t < NB) ? bcount[t] : 0;
  s[t] = mine;
  __syncthreads();
  for (int d = 1; d < 1024; d <<= 1){
    int v = (t >= d) ? s[t-d] : 0;
    __syncthreads();
    s[t] += v;
    __syncthreads();
  }
  if (t < NB) boff[t] = s[t] - mine;
  if (t == NB-1) boff[NB] = s[t];
}

__global__ __launch_bounds__(256) void bscatter_kernel(
    const int* __restrict__ src, const int* __restrict__ dst, int E,
    const int* __restrict__ boff, int* __restrict__ gcur,
    unsigned int* __restrict__ pairs, int NB)
{
  __shared__ int h[1024];
  __shared__ int runbase[1024];
  const int t = threadIdx.x;
  const int e0 = blockIdx.x * 4096;
  for (int i = t; i < NB; i += 256) h[i] = 0;
  __syncthreads();
  int myb[16]; unsigned int myw[16];
  #pragma unroll
  for (int q = 0; q < 16; ++q){
    int e = e0 + q*256 + t;
    int b = -1; unsigned int w = 0;
    if (e < E){
      int d = dst[e];
      b = d >> 6;
      w = ((unsigned int)(d & 63) << 26) | (unsigned int)src[e];
      atomicAdd(&h[b], 1);
    }
    myb[q] = b; myw[q] = w;
  }
  __syncthreads();
  for (int i = t; i < NB; i += 256)
    runbase[i] = h[i] ? atomicAdd(&gcur[i], h[i]) : 0;
  __syncthreads();
  for (int i = t; i < NB; i += 256) h[i] = 0;
  __syncthreads();
  #pragma unroll
  for (int q = 0; q < 16; ++q){
    if (myb[q] >= 0){
      int off = atomicAdd(&h[myb[q]], 1);
      pairs[(size_t)boff[myb[q]] + runbase[myb[q]] + off] = myw[q];
    }
  }
}

__global__ __launch_bounds__(256) void bbuild_kernel(
    const unsigned int* __restrict__ pairs, const int* __restrict__ boff,
    int* __restrict__ rowptr, int* __restrict__ csr, int N)
{
  __shared__ int deg[64], offs[64], cur[64];
  const int b = blockIdx.x;
  const int t = threadIdx.x;
  const int n0 = b << 6;
  const int nNodes = min(64, N - n0);
  const int p0 = boff[b], p1 = boff[b+1];
  const int base = p0 + n0;
  if (t < 64) deg[t] = (t < nNodes) ? 1 : 0;
  __syncthreads();
  for (int i = p0 + t; i < p1; i += 256)
    atomicAdd(&deg[pairs[i] >> 26], 1);
  __syncthreads();
  if (t < 64){
    int x = deg[t];
    #pragma unroll
    for (int d = 1; d < 64; d <<= 1){
      int y = __shfl_up(x, d);
      if (t >= d) x += y;
    }
    offs[t] = x - deg[t];
    cur[t] = 1;
    if (t < nNodes){
      rowptr[n0 + t + 1] = base + x;
      csr[base + x - deg[t]] = n0 + t;
    }
    if (b == 0 && t == 0) rowptr[0] = 0;
  }
  __syncthreads();
  for (int i = p0 + t; i < p1; i += 256){
    unsigned int w = pairs[i];
    int dl = w >> 26;
    int s  = (int)(w & 0x03ffffffu);
    int off = atomicAdd(&cur[dl], 1);
    csr[base + offs[dl] + off] = s;
  }
}

// ================= main kernels (R8, unchanged) =================
__device__ __forceinline__ void gemm_core(
    const unsigned short* __restrict__ A, int lda,
    const unsigned short* __restrict__ BT, int M, int K, int r0,
    unsigned short* a_s, unsigned short* b_s, f32x4 (&acc)[4][4])
{
  const int tid  = threadIdx.x;
  const int lane = tid & 63, wv = tid >> 6;
  const int mh = (wv & 1)*64, nh = (wv >> 1)*64;
  const int l15 = lane & 15, quad = lane >> 4;
  const int srow = tid >> 3, skc = tid & 7;

  #pragma unroll
  for (int i = 0; i < 4; ++i)
    #pragma unroll
    for (int j = 0; j < 4; ++j)
      #pragma unroll
      for (int r = 0; r < 4; ++r) acc[i][j][r] = 0.f;

  for (int k0 = 0; k0 < K; k0 += 64){
    #pragma unroll
    for (int it = 0; it < 4; ++it){
      int row = it*32 + srow;
      int grow = r0 + row;
      uint4 v = make_uint4(0u,0u,0u,0u);
      if (grow < M) v = *(const uint4*)(A + (size_t)grow*lda + k0 + skc*8);
      *(uint4*)(&a_s[row*72 + skc*8]) = v;
    }
    #pragma unroll
    for (int it = 0; it < 4; ++it){
      int row = it*32 + srow;
      uint4 v = *(const uint4*)(BT + (size_t)row*K + k0 + skc*8);
      *(uint4*)(&b_s[row*72 + skc*8]) = v;
    }
    __syncthreads();
    #pragma unroll
    for (int ks = 0; ks < 64; ks += 32){
      bf16x8 af[4], bfr[4];
      #pragma unroll
      for (int i = 0; i < 4; ++i)
        af[i] = *(const bf16x8*)(&a_s[(mh + i*16 + l15)*72 + ks + quad*8]);
      #pragma unroll
      for (int j = 0; j < 4; ++j)
        bfr[j] = *(const bf16x8*)(&b_s[(nh + j*16 + l15)*72 + ks + quad*8]);
      #pragma unroll
      for (int i = 0; i < 4; ++i)
        #pragma unroll
        for (int j = 0; j < 4; ++j)
          acc[i][j] = __builtin_amdgcn_mfma_f32_16x16x32_bf16(bfr[j], af[i], acc[i][j], 0, 0, 0);
    }
    __syncthreads();
  }
}

__global__ __launch_bounds__(256) void gemm_conv1_kernel(
    const unsigned short* __restrict__ xa, const unsigned short* __restrict__ BT1a,
    const unsigned short* __restrict__ BT1b, unsigned short* __restrict__ out1b,
    int M, const float* __restrict__ b1)
{
  __shared__ unsigned short a_s[128*72];
  __shared__ unsigned short b_s[128*72];
  const int hx = blockIdx.x;
  const unsigned short* A  = xa + hx*128;
  const unsigned short* BT = hx ? BT1b : BT1a;
  unsigned short* C = out1b + hx*128;
  const float* bias = b1 + hx*128;
  const int r0 = blockIdx.y*128;
  f32x4 acc[4][4];
  gemm_core(A, 256, BT, M, 128, r0, a_s, b_s, acc);

  const int lane = threadIdx.x & 63, wv = threadIdx.x >> 6;
  const int mh = (wv & 1)*64, nh = (wv >> 1)*64;
  const int l15 = lane & 15, quad = lane >> 4;
  #pragma unroll
  for (int i = 0; i < 4; ++i){
    int m = r0 + mh + i*16 + l15;
    if (m < M){
      #pragma unroll
      for (int j = 0; j < 4; ++j){
        int n = nh + j*16 + quad*4;
        float4 bb = *(const float4*)(bias + n);
        ushort4 u;
        u.x = f2bf(elu_f(acc[i][j][0] + bb.x));
        u.y = f2bf(elu_f(acc[i][j][1] + bb.y));
        u.z = f2bf(elu_f(acc[i][j][2] + bb.z));
        u.w = f2bf(elu_f(acc[i][j][3] + bb.w));
        *(ushort4*)(C + (size_t)m*256 + n) = u;
      }
    }
  }
}

__global__ __launch_bounds__(256) void gemm_conv2_kernel(
    const unsigned short* __restrict__ out1b, const unsigned short* __restrict__ BT2,
    unsigned short* __restrict__ h2b, int M,
    const float* __restrict__ a2s, const float* __restrict__ a2d,
    float* __restrict__ as2, float* __restrict__ ad2)
{
  __shared__ unsigned short a_s[128*72];
  __shared__ unsigned short b_s[128*72];
  __shared__ float part_s[128][2];
  __shared__ float part_d[128][2];
  const int r0 = blockIdx.y*128;
  f32x4 acc[4][4];
  gemm_core(out1b, 256, BT2, M, 256, r0, a_s, b_s, acc);

  const int tid = threadIdx.x;
  const int lane = tid & 63, wv = tid >> 6;
  const int mh = (wv & 1)*64, nh = (wv >> 1)*64;
  const int l15 = lane & 15, quad = lane >> 4;
  #pragma unroll
  for (int i = 0; i < 4; ++i){
    int m = r0 + mh + i*16 + l15;
    float ps = 0.f, pd = 0.f;
    #pragma unroll
    for (int j = 0; j < 4; ++j){
      int n = nh + j*16 + quad*4;
      float4 wsv = *(const float4*)(a2s + n);
      float4 wdv = *(const float4*)(a2d + n);
      float v0 = acc[i][j][0], v1 = acc[i][j][1], v2 = acc[i][j][2], v3 = acc[i][j][3];
      ps += v0*wsv.x + v1*wsv.y + v2*wsv.z + v3*wsv.w;
      pd += v0*wdv.x + v1*wdv.y + v2*wdv.z + v3*wdv.w;
      if (m < M){
        ushort4 u;
        u.x = f2bf(v0); u.y = f2bf(v1); u.z = f2bf(v2); u.w = f2bf(v3);
        *(ushort4*)(h2b + (size_t)m*128 + n) = u;
      }
    }
    ps += __shfl_xor(ps, 16); ps += __shfl_xor(ps, 32);
    pd += __shfl_xor(pd, 16); pd += __shfl_xor(pd, 32);
    if (quad == 0){
      part_s[mh + i*16 + l15][wv >> 1] = ps;
      part_d[mh + i*16 + l15][wv >> 1] = pd;
    }
  }
  __syncthreads();
  if (tid < 128){
    int gm = r0 + tid;
    if (gm < M){
      as2[gm] = part_s[tid][0] + part_s[tid][1];
      ad2[gm] = part_d[tid][0] + part_d[tid][1];
    }
  }
}

__global__ __launch_bounds__(256) void gemm_mlp_kernel(
    const unsigned short* __restrict__ gb, const unsigned short* __restrict__ BT3,
    int M, const float* __restrict__ bm1, const float* __restrict__ Wm2,
    const float* __restrict__ bm2, float* __restrict__ out)
{
  __shared__ unsigned short a_s[128*72];
  __shared__ unsigned short b_s[128*72];
  __shared__ float wm2_s[128*8];
  __shared__ float part[128][2][8];
  const int tid = threadIdx.x;
  {
    int i4 = tid*4;
    *(float4*)(&wm2_s[i4]) = *(const float4*)(Wm2 + i4);
  }
  const int r0 = blockIdx.y*128;
  f32x4 acc[4][4];
  gemm_core(gb, 128, BT3, M, 128, r0, a_s, b_s, acc);

  const int lane = tid & 63, wv = tid >> 6;
  const int mh = (wv & 1)*64, nh = (wv >> 1)*64;
  const int l15 = lane & 15, quad = lane >> 4;
  #pragma unroll
  for (int i = 0; i < 4; ++i){
    float po[8];
    #pragma unroll
    for (int o = 0; o < 8; ++o) po[o] = 0.f;
    #pragma unroll
    for (int j = 0; j < 4; ++j){
      int n = nh + j*16 + quad*4;
      float4 bb = *(const float4*)(bm1 + n);
      #pragma unroll
      for (int r = 0; r < 4; ++r){
        float hcol = fmaxf(acc[i][j][r] + ((const float*)&bb)[r], 0.f);
        const float* wr = &wm2_s[(n + r)*8];
        #pragma unroll
        for (int o = 0; o < 8; ++o) po[o] += hcol*wr[o];
      }
    }
    #pragma unroll
    for (int o = 0; o < 8; ++o){
      po[o] += __shfl_xor(po[o], 16);
      po[o] += __shfl_xor(po[o], 32);
    }
    if (quad == 0){
      #pragma unroll
      for (int o = 0; o < 8; ++o) part[mh + i*16 + l15][wv >> 1][o] = po[o];
    }
  }
  __syncthreads();
  if (tid < 128){
    int gm = r0 + tid;
    if (gm < M){
      float4 o0, o1;
      o0.x = fmaxf(part[tid][0][0] + part[tid][1][0] + bm2[0], 0.f);
      o0.y = fmaxf(part[tid][0][1] + part[tid][1][1] + bm2[1], 0.f);
      o0.z = fmaxf(part[tid][0][2] + part[tid][1][2] + bm2[2], 0.f);
      o0.w = fmaxf(part[tid][0][3] + part[tid][1][3] + bm2[3], 0.f);
      o1.x = fmaxf(part[tid][0][4] + part[tid][1][4] + bm2[4], 0.f);
      o1.y = fmaxf(part[tid][0][5] + part[tid][1][5] + bm2[5], 0.f);
      o1.z = fmaxf(part[tid][0][6] + part[tid][1][6] + bm2[6], 0.f);
      o1.w = fmaxf(part[tid][0][7] + part[tid][1][7] + bm2[7], 0.f);
      *(float4*)(out + (size_t)gm*8)     = o0;
      *(float4*)(out + (size_t)gm*8 + 4) = o1;
    }
  }
}

__global__ __launch_bounds__(256) void agg1x_kernel(
    const unsigned short* __restrict__ xb, const float* __restrict__ as_,
    const float* __restrict__ ad_, const int* __restrict__ rowptr, const int* __restrict__ csr,
    unsigned short* __restrict__ xa, int N)
{
  const int wv = threadIdx.x >> 6, lane = threadIdx.x & 63;
  const int ql = lane & 15;
  const int n = blockIdx.x*16 + wv*4 + (lane >> 4);
  const bool valid = n < N;
  int start = 0, end = 0;
  float2 adv = make_float2(0.f, 0.f);
  if (valid){ start = rowptr[n]; end = rowptr[n+1]; adv = *(const float2*)(ad_ + 2*n); }

  int jl = start + ql;
  bool have = valid && (jl < end);
  int s_l = 0;
  float p0 = 0.f, p1 = 0.f;
  if (have){
    s_l = csr[jl];
    float2 av = *(const float2*)(as_ + 2*s_l);
    p0 = __expf(lrelu(av.x + adv.x));
    p1 = __expf(lrelu(av.y + adv.y));
  }
  float l0 = p0, l1 = p1;
  for (int j = jl + 16; j < end; j += 16){
    int s = csr[j];
    float2 av = *(const float2*)(as_ + 2*s);
    l0 += __expf(lrelu(av.x + adv.x));
    l1 += __expf(lrelu(av.y + adv.y));
  }
  #pragma unroll
  for (int msk = 1; msk <= 8; msk <<= 1){
    l0 += __shfl_xor(l0, msk);
    l1 += __shfl_xor(l1, msk);
  }
  float inv0 = 1.f / fmaxf(l0, 1e-16f);
  float inv1 = 1.f / fmaxf(l1, 1e-16f);
  float a0_l = p0 * inv0;
  float a1_l = p1 * inv1;

  float acc0[8], acc1[8];
  #pragma unroll
  for (int i = 0; i < 8; ++i){ acc0[i] = 0.f; acc1[i] = 0.f; }
  const int c = ql << 3;
  const unsigned short* hp = xb + c;

  int cnt = valid ? min(16, end - start) : 0;
  for (int t = 0; t < cnt; ++t){
    int   sA  = __shfl(s_l, t, 16);
    float a0A = __shfl(a0_l, t, 16);
    float a1A = __shfl(a1_l, t, 16);
    uint4 u = *(const uint4*)(hp + (sA << 7));
    float f0 = bflo(u.x), f1 = bfhi(u.x), f2v = bflo(u.y), f3 = bfhi(u.y);
    float f4 = bflo(u.z), f5 = bfhi(u.z), f6 = bflo(u.w), f7 = bfhi(u.w);
    acc0[0] += a0A*f0; acc0[1] += a0A*f1; acc0[2] += a0A*f2v; acc0[3] += a0A*f3;
    acc0[4] += a0A*f4; acc0[5] += a0A*f5; acc0[6] += a0A*f6;  acc0[7] += a0A*f7;
    acc1[0] += a1A*f0; acc1[1] += a1A*f1; acc1[2] += a1A*f2v; acc1[3] += a1A*f3;
    acc1[4] += a1A*f4; acc1[5] += a1A*f5; acc1[6] += a1A*f6;  acc1[7] += a1A*f7;
  }
  for (int jb = start + 16; jb < end; jb += 16){
    int jl2 = jb + ql;
    int s2 = 0; float a0_2 = 0.f, a1_2 = 0.f;
    if (jl2 < end){
      s2 = csr[jl2];
      float2 av = *(const float2*)(as_ + 2*s2);
      a0_2 = __expf(lrelu(av.x + adv.x)) * inv0;
      a1_2 = __expf(lrelu(av.y + adv.y)) * inv1;
    }
    int cnt2 = min(16, end - jb);
    for (int t2 = 0; t2 < cnt2; ++t2){
      int   sA  = __shfl(s2, t2, 16);
      float a0A = __shfl(a0_2, t2, 16);
      float a1A = __shfl(a1_2, t2, 16);
      uint4 u = *(const uint4*)(hp + (sA << 7));
      float f0 = bflo(u.x), f1 = bfhi(u.x), f2v = bflo(u.y), f3 = bfhi(u.y);
      float f4 = bflo(u.z), f5 = bfhi(u.z), f6 = bflo(u.w), f7 = bfhi(u.w);
      acc0[0] += a0A*f0; acc0[1] += a0A*f1; acc0[2] += a0A*f2v; acc0[3] += a0A*f3;
      acc0[4] += a0A*f4; acc0[5] += a0A*f5; acc0[6] += a0A*f6;  acc0[7] += a0A*f7;
      acc1[0] += a1A*f0; acc1[1] += a1A*f1; acc1[2] += a1A*f2v; acc1[3] += a1A*f3;
      acc1[4] += a1A*f4; acc1[5] += a1A*f5; acc1[6] += a1A*f6;  acc1[7] += a1A*f7;
    }
  }

  if (valid){
    uint4 u0, u1;
    u0.x = packbf(acc0[0], acc0[1]); u0.y = packbf(acc0[2], acc0[3]);
    u0.z = packbf(acc0[4], acc0[5]); u0.w = packbf(acc0[6], acc0[7]);
    u1.x = packbf(acc1[0], acc1[1]); u1.y = packbf(acc1[2], acc1[3]);
    u1.z = packbf(acc1[4], acc1[5]); u1.w = packbf(acc1[6], acc1[7]);
    *(uint4*)(xa + (size_t)n*256 + c)       = u0;
    *(uint4*)(xa + (size_t)n*256 + 128 + c) = u1;
  }
}

__global__ __launch_bounds__(256) void agg2_kernel(
    const unsigned short* __restrict__ h2b, const float* __restrict__ as_,
    const float* __restrict__ ad_, const int* __restrict__ rowptr, const int* __restrict__ csr,
    const float* __restrict__ b2, unsigned short* __restrict__ outb, int N)
{
  const int wv = threadIdx.x >> 6, lane = threadIdx.x & 63;
  const int ql = lane & 15;
  const int n = blockIdx.x*16 + wv*4 + (lane >> 4);
  const bool valid = n < N;
  int start = 0, end = 0;
  float adn = 0.f;
  if (valid){ start = rowptr[n]; end = rowptr[n+1]; adn = ad_[n]; }

  int jl = start + ql;
  bool have = valid && (jl < end);
  int s_l = 0;
  float p_l = 0.f;
  if (have){
    s_l = csr[jl];
    p_l = __expf(lrelu(as_[s_l] + adn));
  }
  float l = p_l;
  for (int j = jl + 16; j < end; j += 16)
    l += __expf(lrelu(as_[csr[j]] + adn));
  #pragma unroll
  for (int msk = 1; msk <= 8; msk <<= 1) l += __shfl_xor(l, msk);
  float inv = 1.f / fmaxf(l, 1e-16f);
  float a_l = p_l * inv;

  float acc[8];
  #pragma unroll
  for (int i = 0; i < 8; ++i) acc[i] = 0.f;
  const int c = ql << 3;
  const unsigned short* hp = h2b + c;

  int cnt = valid ? min(16, end - start) : 0;
  int t = 0;
  for (; t + 1 < cnt; t += 2){
    int   sA = __shfl(s_l, t, 16),  sB = __shfl(s_l, t+1, 16);
    float aA = __shfl(a_l, t, 16),  aB = __shfl(a_l, t+1, 16);
    uint4 uA = *(const uint4*)(hp + (sA << 7));
    uint4 uB = *(const uint4*)(hp + (sB << 7));
    acc[0] += aA*bflo(uA.x) + aB*bflo(uB.x);
    acc[1] += aA*bfhi(uA.x) + aB*bfhi(uB.x);
    acc[2] += aA*bflo(uA.y) + aB*bflo(uB.y);
    acc[3] += aA*bfhi(uA.y) + aB*bfhi(uB.y);
    acc[4] += aA*bflo(uA.z) + aB*bflo(uB.z);
    acc[5] += aA*bfhi(uA.z) + aB*bfhi(uB.z);
    acc[6] += aA*bflo(uA.w) + aB*bflo(uB.w);
    acc[7] += aA*bfhi(uA.w) + aB*bfhi(uB.w);
  }
  if (t < cnt){
    int   sA = __shfl(s_l, t, 16);
    float aA = __shfl(a_l, t, 16);
    uint4 uA = *(const uint4*)(hp + (sA << 7));
    acc[0] += aA*bflo(uA.x); acc[1] += aA*bfhi(uA.x);
    acc[2] += aA*bflo(uA.y); acc[3] += aA*bfhi(uA.y);
    acc[4] += aA*bflo(uA.z); acc[5] += aA*bfhi(uA.z);
    acc[6] += aA*bflo(uA.w); acc[7] += aA*bfhi(uA.w);
  }
  for (int jb = start + 16; jb < end; jb += 16){
    int jl2 = jb + ql;
    int s2 = 0; float a2 = 0.f;
    if (jl2 < end){
      s2 = csr[jl2];
      a2 = __expf(lrelu(as_[s2] + adn)) * inv;
    }
    int cnt2 = min(16, end - jb);
    for (int t2 = 0; t2 < cnt2; ++t2){
      int   sA = __shfl(s2, t2, 16);
      float aA = __shfl(a2, t2, 16);
      uint4 uA = *(const uint4*)(hp + (sA << 7));
      acc[0] += aA*bflo(uA.x); acc[1] += aA*bfhi(uA.x);
      acc[2] += aA*bflo(uA.y); acc[3] += aA*bfhi(uA.y);
      acc[4] += aA*bflo(uA.z); acc[5] += aA*bfhi(uA.z);
      acc[6] += aA*bflo(uA.w); acc[7] += aA*bfhi(uA.w);
    }
  }

  if (valid){
    float4 bb0 = *(const float4*)(b2 + c);
    float4 bb1 = *(const float4*)(b2 + c + 4);
    float o[8];
    o[0]=elu_f(acc[0]+bb0.x); o[1]=elu_f(acc[1]+bb0.y);
    o[2]=elu_f(acc[2]+bb0.z); o[3]=elu_f(acc[3]+bb0.w);
    o[4]=elu_f(acc[4]+bb1.x); o[5]=elu_f(acc[5]+bb1.y);
    o[6]=elu_f(acc[6]+bb1.z); o[7]=elu_f(acc[7]+bb1.w);
    uint4 up;
    up.x = packbf(o[0], o[1]); up.y = packbf(o[2], o[3]);
    up.z = packbf(o[4], o[5]); up.w = packbf(o[6], o[7]);
    *(uint4*)(outb + (size_t)n*128 + c) = up;
  }
}

extern "C" void kernel_launch(void* const* d_in, const int* in_sizes, int n_in,
                              void* d_out, int out_size, void* d_ws, size_t ws_size,
                              hipStream_t stream)
{
  (void)n_in; (void)out_size; (void)ws_size;
  const float* x   = (const float*)d_in[0];
  const int*   ei  = (const int*)d_in[1];
  const float* W1  = (const float*)d_in[2];
  const float* a1s = (const float*)d_in[3];
  const float* a1d = (const float*)d_in[4];
  const float* b1  = (const float*)d_in[5];
  const float* W2  = (const float*)d_in[6];
  const float* a2s = (const float*)d_in[7];
  const float* a2d = (const float*)d_in[8];
  const float* b2  = (const float*)d_in[9];
  const float* Wm1 = (const float*)d_in[10];
  const float* bm1 = (const float*)d_in[11];
  const float* Wm2 = (const float*)d_in[12];
  const float* bm2 = (const float*)d_in[13];
  float* out = (float*)d_out;

  int N = in_sizes[0] / 128;
  int E = in_sizes[1] / 2;
  int NB = (N + 63) >> 6;
  const int* srcp = ei;
  const int* dstp = ei + E;

  char* ws = (char*)d_ws;
  unsigned short* xb    = (unsigned short*)ws;
  unsigned short* xa    = (unsigned short*)(ws + (size_t)N*256);
  unsigned short* out1b = (unsigned short*)(ws + (size_t)N*768);
  unsigned short* h2b   = (unsigned short*)(ws + (size_t)N*1280);
  char* tail = ws + (size_t)N*1536;
  unsigned short* BT1a = (unsigned short*)tail;
  unsigned short* BT1b = BT1a + 128*128;
  unsigned short* BT2  = BT1b + 128*128;
  unsigned short* BT3  = BT2 + 128*256;
  float* va   = (float*)(BT3 + 128*128);
  float* as1  = va + 512;
  float* ad1  = as1 + (size_t)2*N;
  float* as2  = ad1 + (size_t)2*N;
  float* ad2  = as2 + N;
  int* bcount = (int*)(ad2 + N);
  int* boff   = bcount + 1024;
  int* gcur   = boff + 1032;
  int* rowptr = gcur + 1024;
  int* csr    = rowptr + N + 1;
  unsigned int* pairs = (unsigned int*)(csr + E + N);

  unsigned short* gb = xb;            // xb dead after agg1x

  // ---- CSR/prep: cooperative single dispatch if supported, else 5-kernel chain ----
  int coopAttr = 0;
  hipDeviceGetAttribute(&coopAttr, hipDeviceAttributeCooperativeLaunch, 0);
  bool coopDone = false;
  if (coopAttr){
    // Fixed conservative grid: 512 blocks = 2 blocks/CU (8KB LDS, VGPR<=256
    // via __launch_bounds__(256,2)) -> co-residency guaranteed by arithmetic.
    int gridA = 512;
    int maxA = (N*32 + 255)/256;
    if (gridA > maxA) gridA = maxA;
    void* argsA[] = {
      (void*)&x, (void*)&xb, (void*)&N,
      (void*)&W1, (void*)&BT1a, (void*)&BT1b,
      (void*)&W2, (void*)&BT2, (void*)&Wm1, (void*)&BT3,
      (void*)&a1s, (void*)&a1d, (void*)&va,
      (void*)&as1, (void*)&ad1,
      (void*)&srcp, (void*)&dstp, (void*)&E,
      (void*)&bcount, (void*)&boff, (void*)&gcur,
      (void*)&pairs, (void*)&rowptr, (void*)&csr, (void*)&NB
    };
    hipError_t rc = hipLaunchCooperativeKernel((const void*)build_coop, dim3(gridA),
                                               dim3(256), argsA, 0, stream);
    coopDone = (rc == hipSuccess);
  }
  if (!coopDone){
    const int nbConv = (N*32 + 255)/256;
    const int prepTotal = 128*128 + 128*256 + 128*128 + 512 + 2048;
    prep_kernel<<<(prepTotal + 255)/256, 256, 0, stream>>>(
        W1, BT1a, BT1b, W2, BT2, Wm1, BT3, a1s, a1d, va, bcount, gcur, NB);
    f2bf_hist_kernel<<<nbConv + 64, 256, 0, stream>>>(x, xb, N, va, as1, ad1,
                                                      dstp, E, bcount, NB, nbConv);
    bscan_kernel<<<1, 1024, 0, stream>>>(bcount, boff, NB);
    bscatter_kernel<<<(E + 4095)/4096, 256, 0, stream>>>(srcp, dstp, E, boff, gcur, pairs, NB);
    bbuild_kernel<<<NB, 256, 0, stream>>>(pairs, boff, rowptr, csr, N);
  }

  const int gy   = (N + 127) / 128;
  const int nb16 = (N + 15) / 16;

  // ---- main pipeline (R8, unchanged) ----
  agg1x_kernel<<<nb16, 256, 0, stream>>>(xb, as1, ad1, rowptr, csr, xa, N);
  gemm_conv1_kernel<<<dim3(2, gy), 256, 0, stream>>>(xa, BT1a, BT1b, out1b, N, b1);
  gemm_conv2_kernel<<<dim3(1, gy), 256, 0, stream>>>(out1b, BT2, h2b, N, a2s, a2d, as2, ad2);
  agg2_kernel<<<nb16, 256, 0, stream>>>(h2b, as2, ad2, rowptr, csr, b2, gb, N);
  gemm_mlp_kernel<<<dim3(1, gy), 256, 0, stream>>>(gb, BT3, N, bm1, Wm2, bm2, out);
}

// Round 11
// 267.668 us; speedup vs baseline: 1.8183x; 1.8183x over previous
//
#include <hip/hip_runtime.h>
#include <hip/hip_bf16.h>

// GATNet: 2x GATConv + 2-layer MLP.
// R10 -> R11: cooperative grid.sync proven pathological on gfx950 (256us,
// VALU 1% -> spin barrier). Reverted to the proven R8 9/10-dispatch form with:
//  (1) unroll-4 gather loops in agg1x/agg2 (4 independent uint4 loads in
//      flight per lane -> 4x memory-level parallelism on the latency-bound
//      random gathers);
//  (2) bscan dispatch deleted: each bscatter block redundantly scans the
//      <=1024 bucket counts in LDS (overlapped, ~1us); block 0 publishes
//      boff for bbuild (next dispatch -> visibility guaranteed). 9 dispatches.

__device__ __forceinline__ float lrelu(float x){ return x > 0.f ? x : 0.2f*x; }
__device__ __forceinline__ float elu_f(float x){ return x > 0.f ? x : __expf(x) - 1.f; }
__device__ __forceinline__ unsigned short f2bf(float f){
  __hip_bfloat16 h = __float2bfloat16(f);   // RNE
  return *reinterpret_cast<unsigned short*>(&h);
}
__device__ __forceinline__ float bflo(unsigned int u){ return __uint_as_float(u << 16); }
__device__ __forceinline__ float bfhi(unsigned int u){ return __uint_as_float(u & 0xffff0000u); }
__device__ __forceinline__ unsigned int packbf(float a, float b){
  return (unsigned int)f2bf(a) | ((unsigned int)f2bf(b) << 16);
}

typedef __attribute__((ext_vector_type(8))) short bf16x8;
typedef __attribute__((ext_vector_type(4))) float f32x4;

// ---------------- prep: weight transposes + va + zero bucket arrays ----------------
__global__ void prep_kernel(const float* __restrict__ W1, unsigned short* __restrict__ BT1a,
                            unsigned short* __restrict__ BT1b,
                            const float* __restrict__ W2, unsigned short* __restrict__ BT2,
                            const float* __restrict__ Wm1, unsigned short* __restrict__ BT3,
                            const float* __restrict__ a1s, const float* __restrict__ a1d,
                            float* __restrict__ va, int* __restrict__ bcount,
                            int* __restrict__ gcur, int NB){
  int idx = blockIdx.x*256 + threadIdx.x;
  const int S1 = 128*128, S2 = 128*256, S3 = 128*128;
  if (idx < S1){
    int n = idx >> 7, k = idx & 127;
    BT1a[idx] = f2bf(W1[(size_t)k*256 + n]);
    BT1b[idx] = f2bf(W1[(size_t)k*256 + 128 + n]);
  } else if (idx < S1 + S2){
    int j = idx - S1;
    int n = j >> 8, k = j & 255;
    BT2[j] = f2bf(W2[(size_t)k*128 + n]);
  } else if (idx < S1 + S2 + S3){
    int j = idx - S1 - S2;
    int n = j >> 7, k = j & 127;
    BT3[j] = f2bf(Wm1[(size_t)k*128 + n]);
  } else if (idx < S1 + S2 + S3 + 512){
    int j = idx - S1 - S2 - S3;
    int v = j >> 7, k = j & 127;
    const float* avec = (v < 2) ? a1s : a1d;
    int head = v & 1;
    const float* wrow = W1 + (size_t)k*256 + head*128;
    const float* arow = avec + head*128;
    float s = 0.f;
    #pragma unroll 8
    for (int f = 0; f < 128; ++f) s += wrow[f]*arow[f];
    va[j] = s;
  } else if (idx < S1 + S2 + S3 + 512 + 2048){
    int z = idx - (S1 + S2 + S3 + 512);
    if (z < 1024){ if (z < NB) bcount[z] = 0; }
    else { z -= 1024; if (z < NB) gcur[z] = 0; }
  }
}

// ---------------- f2bf + conv1 alpha dots + edge histogram ----------------
__global__ __launch_bounds__(256) void f2bf_hist_kernel(
    const float* __restrict__ x, unsigned short* __restrict__ xb, int N,
    const float* __restrict__ va, float* __restrict__ as1, float* __restrict__ ad1,
    const int* __restrict__ dst, int E, int* __restrict__ bcount, int NB, int nbConv)
{
  __shared__ int h[1024];
  if ((int)blockIdx.x < nbConv){
    int i = blockIdx.x*256 + threadIdx.x;
    int total = N*32;
    float4 v = make_float4(0.f,0.f,0.f,0.f);
    if (i < total){
      v = ((const float4*)x)[i];
      ushort4 u; u.x=f2bf(v.x); u.y=f2bf(v.y); u.z=f2bf(v.z); u.w=f2bf(v.w);
      ((ushort4*)xb)[i] = u;
    }
    int c = (i & 31) << 2;
    float4 vs0 = *(const float4*)(va + c);
    float4 vs1 = *(const float4*)(va + 128 + c);
    float4 vd0 = *(const float4*)(va + 256 + c);
    float4 vd1 = *(const float4*)(va + 384 + c);
    float s0 = v.x*vs0.x + v.y*vs0.y + v.z*vs0.z + v.w*vs0.w;
    float s1 = v.x*vs1.x + v.y*vs1.y + v.z*vs1.z + v.w*vs1.w;
    float d0 = v.x*vd0.x + v.y*vd0.y + v.z*vd0.z + v.w*vd0.w;
    float d1 = v.x*vd1.x + v.y*vd1.y + v.z*vd1.z + v.w*vd1.w;
    #pragma unroll
    for (int m = 1; m <= 16; m <<= 1){
      s0 += __shfl_xor(s0, m); s1 += __shfl_xor(s1, m);
      d0 += __shfl_xor(d0, m); d1 += __shfl_xor(d1, m);
    }
    if ((i & 31) == 0 && i < total){
      int n = i >> 5;
      *(float2*)(as1 + 2*n) = make_float2(s0, s1);
      *(float2*)(ad1 + 2*n) = make_float2(d0, d1);
    }
  } else {
    for (int i = threadIdx.x; i < NB; i += 256) h[i] = 0;
    __syncthreads();
    int b0 = blockIdx.x - nbConv;
    for (int e = b0*256 + threadIdx.x; e < E; e += 64*256)
      atomicAdd(&h[dst[e] >> 6], 1);
    __syncthreads();
    for (int i = threadIdx.x; i < NB; i += 256)
      if (h[i]) atomicAdd(&bcount[i], h[i]);
  }
}

// ---------------- bscatter: redundant LDS scan + aggregated scatter ----------------
__global__ __launch_bounds__(256) void bscatter_kernel(
    const int* __restrict__ src, const int* __restrict__ dst, int E,
    const int* __restrict__ bcount, int* __restrict__ gcur,
    unsigned int* __restrict__ pairs, int* __restrict__ boff, int NB)
{
  __shared__ int h[1024];
  __shared__ int runbase[1024];
  __shared__ int sc[1024];
  const int t = threadIdx.x;

  // inclusive scan of bcount (NB <= 1024) in LDS, every block (overlapped)
  #pragma unroll
  for (int q = 0; q < 4; ++q){
    int i = t + q*256;
    sc[i] = (i < NB) ? bcount[i] : 0;
  }
  __syncthreads();
  for (int d = 1; d < 1024; d <<= 1){
    int v[4];
    #pragma unroll
    for (int q = 0; q < 4; ++q){
      int idx = t + q*256;
      v[q] = (idx >= d) ? sc[idx - d] : 0;
    }
    __syncthreads();
    #pragma unroll
    for (int q = 0; q < 4; ++q) sc[t + q*256] += v[q];
    __syncthreads();
  }
  if (blockIdx.x == 0){
    for (int i = t; i < NB; i += 256) boff[i] = i ? sc[i-1] : 0;
    if (t == 0) boff[NB] = sc[NB-1];
  }

  const int e0 = blockIdx.x * 4096;
  for (int i = t; i < NB; i += 256) h[i] = 0;
  __syncthreads();
  int myb[16]; unsigned int myw[16];
  #pragma unroll
  for (int q = 0; q < 16; ++q){
    int e = e0 + q*256 + t;
    int b = -1; unsigned int w = 0;
    if (e < E){
      int d = dst[e];
      b = d >> 6;
      w = ((unsigned int)(d & 63) << 26) | (unsigned int)src[e];
      atomicAdd(&h[b], 1);
    }
    myb[q] = b; myw[q] = w;
  }
  __syncthreads();
  for (int i = t; i < NB; i += 256)
    runbase[i] = h[i] ? atomicAdd(&gcur[i], h[i]) : 0;
  __syncthreads();
  for (int i = t; i < NB; i += 256) h[i] = 0;
  __syncthreads();
  #pragma unroll
  for (int q = 0; q < 16; ++q){
    if (myb[q] >= 0){
      int off = atomicAdd(&h[myb[q]], 1);
      int base = myb[q] ? sc[myb[q]-1] : 0;
      pairs[(size_t)base + runbase[myb[q]] + off] = myw[q];
    }
  }
}

__global__ __launch_bounds__(256) void bbuild_kernel(
    const unsigned int* __restrict__ pairs, const int* __restrict__ boff,
    int* __restrict__ rowptr, int* __restrict__ csr, int N)
{
  __shared__ int deg[64], offs[64], cur[64];
  const int b = blockIdx.x;
  const int t = threadIdx.x;
  const int n0 = b << 6;
  const int nNodes = min(64, N - n0);
  const int p0 = boff[b], p1 = boff[b+1];
  const int base = p0 + n0;
  if (t < 64) deg[t] = (t < nNodes) ? 1 : 0;
  __syncthreads();
  for (int i = p0 + t; i < p1; i += 256)
    atomicAdd(&deg[pairs[i] >> 26], 1);
  __syncthreads();
  if (t < 64){
    int x = deg[t];
    #pragma unroll
    for (int d = 1; d < 64; d <<= 1){
      int y = __shfl_up(x, d);
      if (t >= d) x += y;
    }
    offs[t] = x - deg[t];
    cur[t] = 1;
    if (t < nNodes){
      rowptr[n0 + t + 1] = base + x;
      csr[base + x - deg[t]] = n0 + t;
    }
    if (b == 0 && t == 0) rowptr[0] = 0;
  }
  __syncthreads();
  for (int i = p0 + t; i < p1; i += 256){
    unsigned int w = pairs[i];
    int dl = w >> 26;
    int s  = (int)(w & 0x03ffffffu);
    int off = atomicAdd(&cur[dl], 1);
    csr[base + offs[dl] + off] = s;
  }
}

// ---------------- GEMM core: 128x128 tile, BK=64, bf16 MFMA ----------------
__device__ __forceinline__ void gemm_core(
    const unsigned short* __restrict__ A, int lda,
    const unsigned short* __restrict__ BT, int M, int K, int r0,
    unsigned short* a_s, unsigned short* b_s, f32x4 (&acc)[4][4])
{
  const int tid  = threadIdx.x;
  const int lane = tid & 63, wv = tid >> 6;
  const int mh = (wv & 1)*64, nh = (wv >> 1)*64;
  const int l15 = lane & 15, quad = lane >> 4;
  const int srow = tid >> 3, skc = tid & 7;

  #pragma unroll
  for (int i = 0; i < 4; ++i)
    #pragma unroll
    for (int j = 0; j < 4; ++j)
      #pragma unroll
      for (int r = 0; r < 4; ++r) acc[i][j][r] = 0.f;

  for (int k0 = 0; k0 < K; k0 += 64){
    #pragma unroll
    for (int it = 0; it < 4; ++it){
      int row = it*32 + srow;
      int grow = r0 + row;
      uint4 v = make_uint4(0u,0u,0u,0u);
      if (grow < M) v = *(const uint4*)(A + (size_t)grow*lda + k0 + skc*8);
      *(uint4*)(&a_s[row*72 + skc*8]) = v;
    }
    #pragma unroll
    for (int it = 0; it < 4; ++it){
      int row = it*32 + srow;
      uint4 v = *(const uint4*)(BT + (size_t)row*K + k0 + skc*8);
      *(uint4*)(&b_s[row*72 + skc*8]) = v;
    }
    __syncthreads();
    #pragma unroll
    for (int ks = 0; ks < 64; ks += 32){
      bf16x8 af[4], bfr[4];
      #pragma unroll
      for (int i = 0; i < 4; ++i)
        af[i] = *(const bf16x8*)(&a_s[(mh + i*16 + l15)*72 + ks + quad*8]);
      #pragma unroll
      for (int j = 0; j < 4; ++j)
        bfr[j] = *(const bf16x8*)(&b_s[(nh + j*16 + l15)*72 + ks + quad*8]);
      #pragma unroll
      for (int i = 0; i < 4; ++i)
        #pragma unroll
        for (int j = 0; j < 4; ++j)
          acc[i][j] = __builtin_amdgcn_mfma_f32_16x16x32_bf16(bfr[j], af[i], acc[i][j], 0, 0, 0);
    }
    __syncthreads();
  }
}

__global__ __launch_bounds__(256) void gemm_conv1_kernel(
    const unsigned short* __restrict__ xa, const unsigned short* __restrict__ BT1a,
    const unsigned short* __restrict__ BT1b, unsigned short* __restrict__ out1b,
    int M, const float* __restrict__ b1)
{
  __shared__ unsigned short a_s[128*72];
  __shared__ unsigned short b_s[128*72];
  const int hx = blockIdx.x;
  const unsigned short* A  = xa + hx*128;
  const unsigned short* BT = hx ? BT1b : BT1a;
  unsigned short* C = out1b + hx*128;
  const float* bias = b1 + hx*128;
  const int r0 = blockIdx.y*128;
  f32x4 acc[4][4];
  gemm_core(A, 256, BT, M, 128, r0, a_s, b_s, acc);

  const int lane = threadIdx.x & 63, wv = threadIdx.x >> 6;
  const int mh = (wv & 1)*64, nh = (wv >> 1)*64;
  const int l15 = lane & 15, quad = lane >> 4;
  #pragma unroll
  for (int i = 0; i < 4; ++i){
    int m = r0 + mh + i*16 + l15;
    if (m < M){
      #pragma unroll
      for (int j = 0; j < 4; ++j){
        int n = nh + j*16 + quad*4;
        float4 bb = *(const float4*)(bias + n);
        ushort4 u;
        u.x = f2bf(elu_f(acc[i][j][0] + bb.x));
        u.y = f2bf(elu_f(acc[i][j][1] + bb.y));
        u.z = f2bf(elu_f(acc[i][j][2] + bb.z));
        u.w = f2bf(elu_f(acc[i][j][3] + bb.w));
        *(ushort4*)(C + (size_t)m*256 + n) = u;
      }
    }
  }
}

__global__ __launch_bounds__(256) void gemm_conv2_kernel(
    const unsigned short* __restrict__ out1b, const unsigned short* __restrict__ BT2,
    unsigned short* __restrict__ h2b, int M,
    const float* __restrict__ a2s, const float* __restrict__ a2d,
    float* __restrict__ as2, float* __restrict__ ad2)
{
  __shared__ unsigned short a_s[128*72];
  __shared__ unsigned short b_s[128*72];
  __shared__ float part_s[128][2];
  __shared__ float part_d[128][2];
  const int r0 = blockIdx.y*128;
  f32x4 acc[4][4];
  gemm_core(out1b, 256, BT2, M, 256, r0, a_s, b_s, acc);

  const int tid = threadIdx.x;
  const int lane = tid & 63, wv = tid >> 6;
  const int mh = (wv & 1)*64, nh = (wv >> 1)*64;
  const int l15 = lane & 15, quad = lane >> 4;
  #pragma unroll
  for (int i = 0; i < 4; ++i){
    int m = r0 + mh + i*16 + l15;
    float ps = 0.f, pd = 0.f;
    #pragma unroll
    for (int j = 0; j < 4; ++j){
      int n = nh + j*16 + quad*4;
      float4 wsv = *(const float4*)(a2s + n);
      float4 wdv = *(const float4*)(a2d + n);
      float v0 = acc[i][j][0], v1 = acc[i][j][1], v2 = acc[i][j][2], v3 = acc[i][j][3];
      ps += v0*wsv.x + v1*wsv.y + v2*wsv.z + v3*wsv.w;
      pd += v0*wdv.x + v1*wdv.y + v2*wdv.z + v3*wdv.w;
      if (m < M){
        ushort4 u;
        u.x = f2bf(v0); u.y = f2bf(v1); u.z = f2bf(v2); u.w = f2bf(v3);
        *(ushort4*)(h2b + (size_t)m*128 + n) = u;
      }
    }
    ps += __shfl_xor(ps, 16); ps += __shfl_xor(ps, 32);
    pd += __shfl_xor(pd, 16); pd += __shfl_xor(pd, 32);
    if (quad == 0){
      part_s[mh + i*16 + l15][wv >> 1] = ps;
      part_d[mh + i*16 + l15][wv >> 1] = pd;
    }
  }
  __syncthreads();
  if (tid < 128){
    int gm = r0 + tid;
    if (gm < M){
      as2[gm] = part_s[tid][0] + part_s[tid][1];
      ad2[gm] = part_d[tid][0] + part_d[tid][1];
    }
  }
}

__global__ __launch_bounds__(256) void gemm_mlp_kernel(
    const unsigned short* __restrict__ gb, const unsigned short* __restrict__ BT3,
    int M, const float* __restrict__ bm1, const float* __restrict__ Wm2,
    const float* __restrict__ bm2, float* __restrict__ out)
{
  __shared__ unsigned short a_s[128*72];
  __shared__ unsigned short b_s[128*72];
  __shared__ float wm2_s[128*8];
  __shared__ float part[128][2][8];
  const int tid = threadIdx.x;
  {
    int i4 = tid*4;
    *(float4*)(&wm2_s[i4]) = *(const float4*)(Wm2 + i4);
  }
  const int r0 = blockIdx.y*128;
  f32x4 acc[4][4];
  gemm_core(gb, 128, BT3, M, 128, r0, a_s, b_s, acc);

  const int lane = tid & 63, wv = tid >> 6;
  const int mh = (wv & 1)*64, nh = (wv >> 1)*64;
  const int l15 = lane & 15, quad = lane >> 4;
  #pragma unroll
  for (int i = 0; i < 4; ++i){
    float po[8];
    #pragma unroll
    for (int o = 0; o < 8; ++o) po[o] = 0.f;
    #pragma unroll
    for (int j = 0; j < 4; ++j){
      int n = nh + j*16 + quad*4;
      float4 bb = *(const float4*)(bm1 + n);
      #pragma unroll
      for (int r = 0; r < 4; ++r){
        float hcol = fmaxf(acc[i][j][r] + ((const float*)&bb)[r], 0.f);
        const float* wr = &wm2_s[(n + r)*8];
        #pragma unroll
        for (int o = 0; o < 8; ++o) po[o] += hcol*wr[o];
      }
    }
    #pragma unroll
    for (int o = 0; o < 8; ++o){
      po[o] += __shfl_xor(po[o], 16);
      po[o] += __shfl_xor(po[o], 32);
    }
    if (quad == 0){
      #pragma unroll
      for (int o = 0; o < 8; ++o) part[mh + i*16 + l15][wv >> 1][o] = po[o];
    }
  }
  __syncthreads();
  if (tid < 128){
    int gm = r0 + tid;
    if (gm < M){
      float4 o0, o1;
      o0.x = fmaxf(part[tid][0][0] + part[tid][1][0] + bm2[0], 0.f);
      o0.y = fmaxf(part[tid][0][1] + part[tid][1][1] + bm2[1], 0.f);
      o0.z = fmaxf(part[tid][0][2] + part[tid][1][2] + bm2[2], 0.f);
      o0.w = fmaxf(part[tid][0][3] + part[tid][1][3] + bm2[3], 0.f);
      o1.x = fmaxf(part[tid][0][4] + part[tid][1][4] + bm2[4], 0.f);
      o1.y = fmaxf(part[tid][0][5] + part[tid][1][5] + bm2[5], 0.f);
      o1.z = fmaxf(part[tid][0][6] + part[tid][1][6] + bm2[6], 0.f);
      o1.w = fmaxf(part[tid][0][7] + part[tid][1][7] + bm2[7], 0.f);
      *(float4*)(out + (size_t)gm*8)     = o0;
      *(float4*)(out + (size_t)gm*8 + 4) = o1;
    }
  }
}

// ---------------- agg1x: 4 nodes/wave, 16 lanes/node, unroll-4 gather ----------------
__global__ __launch_bounds__(256) void agg1x_kernel(
    const unsigned short* __restrict__ xb, const float* __restrict__ as_,
    const float* __restrict__ ad_, const int* __restrict__ rowptr, const int* __restrict__ csr,
    unsigned short* __restrict__ xa, int N)
{
  const int wv = threadIdx.x >> 6, lane = threadIdx.x & 63;
  const int ql = lane & 15;
  const int n = blockIdx.x*16 + wv*4 + (lane >> 4);
  const bool valid = n < N;
  int start = 0, end = 0;
  float2 adv = make_float2(0.f, 0.f);
  if (valid){ start = rowptr[n]; end = rowptr[n+1]; adv = *(const float2*)(ad_ + 2*n); }

  int jl = start + ql;
  bool have = valid && (jl < end);
  int s_l = 0;
  float p0 = 0.f, p1 = 0.f;
  if (have){
    s_l = csr[jl];
    float2 av = *(const float2*)(as_ + 2*s_l);
    p0 = __expf(lrelu(av.x + adv.x));
    p1 = __expf(lrelu(av.y + adv.y));
  }
  float l0 = p0, l1 = p1;
  for (int j = jl + 16; j < end; j += 16){
    int s = csr[j];
    float2 av = *(const float2*)(as_ + 2*s);
    l0 += __expf(lrelu(av.x + adv.x));
    l1 += __expf(lrelu(av.y + adv.y));
  }
  #pragma unroll
  for (int msk = 1; msk <= 8; msk <<= 1){
    l0 += __shfl_xor(l0, msk);
    l1 += __shfl_xor(l1, msk);
  }
  float inv0 = 1.f / fmaxf(l0, 1e-16f);
  float inv1 = 1.f / fmaxf(l1, 1e-16f);
  float a0_l = p0 * inv0;
  float a1_l = p1 * inv1;

  float acc0[8], acc1[8];
  #pragma unroll
  for (int i = 0; i < 8; ++i){ acc0[i] = 0.f; acc1[i] = 0.f; }
  const int c = ql << 3;
  const unsigned short* hp = xb + c;

  int cnt = valid ? min(16, end - start) : 0;
  int t = 0;
  for (; t + 3 < cnt; t += 4){
    int   sA  = __shfl(s_l, t, 16),    sB  = __shfl(s_l, t+1, 16);
    int   sC  = __shfl(s_l, t+2, 16),  sD  = __shfl(s_l, t+3, 16);
    float a0A = __shfl(a0_l, t, 16),   a0B = __shfl(a0_l, t+1, 16);
    float a0C = __shfl(a0_l, t+2, 16), a0D = __shfl(a0_l, t+3, 16);
    float a1A = __shfl(a1_l, t, 16),   a1B = __shfl(a1_l, t+1, 16);
    float a1C = __shfl(a1_l, t+2, 16), a1D = __shfl(a1_l, t+3, 16);
    uint4 uA = *(const uint4*)(hp + (sA << 7));
    uint4 uB = *(const uint4*)(hp + (sB << 7));
    uint4 uC = *(const uint4*)(hp + (sC << 7));
    uint4 uD = *(const uint4*)(hp + (sD << 7));
    float fA[8] = {bflo(uA.x),bfhi(uA.x),bflo(uA.y),bfhi(uA.y),bflo(uA.z),bfhi(uA.z),bflo(uA.w),bfhi(uA.w)};
    float fB[8] = {bflo(uB.x),bfhi(uB.x),bflo(uB.y),bfhi(uB.y),bflo(uB.z),bfhi(uB.z),bflo(uB.w),bfhi(uB.w)};
    float fC[8] = {bflo(uC.x),bfhi(uC.x),bflo(uC.y),bfhi(uC.y),bflo(uC.z),bfhi(uC.z),bflo(uC.w),bfhi(uC.w)};
    float fD[8] = {bflo(uD.x),bfhi(uD.x),bflo(uD.y),bfhi(uD.y),bflo(uD.z),bfhi(uD.z),bflo(uD.w),bfhi(uD.w)};
    #pragma unroll
    for (int i = 0; i < 8; ++i){
      acc0[i] += a0A*fA[i] + a0B*fB[i] + a0C*fC[i] + a0D*fD[i];
      acc1[i] += a1A*fA[i] + a1B*fB[i] + a1C*fC[i] + a1D*fD[i];
    }
  }
  for (; t < cnt; ++t){
    int   sA  = __shfl(s_l, t, 16);
    float a0A = __shfl(a0_l, t, 16);
    float a1A = __shfl(a1_l, t, 16);
    uint4 u = *(const uint4*)(hp + (sA << 7));
    float fA[8] = {bflo(u.x),bfhi(u.x),bflo(u.y),bfhi(u.y),bflo(u.z),bfhi(u.z),bflo(u.w),bfhi(u.w)};
    #pragma unroll
    for (int i = 0; i < 8; ++i){
      acc0[i] += a0A*fA[i];
      acc1[i] += a1A*fA[i];
    }
  }
  // rare chunks beyond 16 edges
  for (int jb = start + 16; jb < end; jb += 16){
    int jl2 = jb + ql;
    int s2 = 0; float a0_2 = 0.f, a1_2 = 0.f;
    if (jl2 < end){
      s2 = csr[jl2];
      float2 av = *(const float2*)(as_ + 2*s2);
      a0_2 = __expf(lrelu(av.x + adv.x)) * inv0;
      a1_2 = __expf(lrelu(av.y + adv.y)) * inv1;
    }
    int cnt2 = min(16, end - jb);
    for (int t2 = 0; t2 < cnt2; ++t2){
      int   sA  = __shfl(s2, t2, 16);
      float a0A = __shfl(a0_2, t2, 16);
      float a1A = __shfl(a1_2, t2, 16);
      uint4 u = *(const uint4*)(hp + (sA << 7));
      float fA[8] = {bflo(u.x),bfhi(u.x),bflo(u.y),bfhi(u.y),bflo(u.z),bfhi(u.z),bflo(u.w),bfhi(u.w)};
      #pragma unroll
      for (int i = 0; i < 8; ++i){
        acc0[i] += a0A*fA[i];
        acc1[i] += a1A*fA[i];
      }
    }
  }

  if (valid){
    uint4 u0, u1;
    u0.x = packbf(acc0[0], acc0[1]); u0.y = packbf(acc0[2], acc0[3]);
    u0.z = packbf(acc0[4], acc0[5]); u0.w = packbf(acc0[6], acc0[7]);
    u1.x = packbf(acc1[0], acc1[1]); u1.y = packbf(acc1[2], acc1[3]);
    u1.z = packbf(acc1[4], acc1[5]); u1.w = packbf(acc1[6], acc1[7]);
    *(uint4*)(xa + (size_t)n*256 + c)       = u0;
    *(uint4*)(xa + (size_t)n*256 + 128 + c) = u1;
  }
}

// ---------------- agg2: 4 nodes/wave, 16 lanes/node, unroll-4 gather ----------------
__global__ __launch_bounds__(256) void agg2_kernel(
    const unsigned short* __restrict__ h2b, const float* __restrict__ as_,
    const float* __restrict__ ad_, const int* __restrict__ rowptr, const int* __restrict__ csr,
    const float* __restrict__ b2, unsigned short* __restrict__ outb, int N)
{
  const int wv = threadIdx.x >> 6, lane = threadIdx.x & 63;
  const int ql = lane & 15;
  const int n = blockIdx.x*16 + wv*4 + (lane >> 4);
  const bool valid = n < N;
  int start = 0, end = 0;
  float adn = 0.f;
  if (valid){ start = rowptr[n]; end = rowptr[n+1]; adn = ad_[n]; }

  int jl = start + ql;
  bool have = valid && (jl < end);
  int s_l = 0;
  float p_l = 0.f;
  if (have){
    s_l = csr[jl];
    p_l = __expf(lrelu(as_[s_l] + adn));
  }
  float l = p_l;
  for (int j = jl + 16; j < end; j += 16)
    l += __expf(lrelu(as_[csr[j]] + adn));
  #pragma unroll
  for (int msk = 1; msk <= 8; msk <<= 1) l += __shfl_xor(l, msk);
  float inv = 1.f / fmaxf(l, 1e-16f);
  float a_l = p_l * inv;

  float acc[8];
  #pragma unroll
  for (int i = 0; i < 8; ++i) acc[i] = 0.f;
  const int c = ql << 3;
  const unsigned short* hp = h2b + c;

  int cnt = valid ? min(16, end - start) : 0;
  int t = 0;
  for (; t + 3 < cnt; t += 4){
    int   sA = __shfl(s_l, t, 16),   sB = __shfl(s_l, t+1, 16);
    int   sC = __shfl(s_l, t+2, 16), sD = __shfl(s_l, t+3, 16);
    float aA = __shfl(a_l, t, 16),   aB = __shfl(a_l, t+1, 16);
    float aC = __shfl(a_l, t+2, 16), aD = __shfl(a_l, t+3, 16);
    uint4 uA = *(const uint4*)(hp + (sA << 7));
    uint4 uB = *(const uint4*)(hp + (sB << 7));
    uint4 uC = *(const uint4*)(hp + (sC << 7));
    uint4 uD = *(const uint4*)(hp + (sD << 7));
    float fA[8] = {bflo(uA.x),bfhi(uA.x),bflo(uA.y),bfhi(uA.y),bflo(uA.z),bfhi(uA.z),bflo(uA.w),bfhi(uA.w)};
    float fB[8] = {bflo(uB.x),bfhi(uB.x),bflo(uB.y),bfhi(uB.y),bflo(uB.z),bfhi(uB.z),bflo(uB.w),bfhi(uB.w)};
    float fC[8] = {bflo(uC.x),bfhi(uC.x),bflo(uC.y),bfhi(uC.y),bflo(uC.z),bfhi(uC.z),bflo(uC.w),bfhi(uC.w)};
    float fD[8] = {bflo(uD.x),bfhi(uD.x),bflo(uD.y),bfhi(uD.y),bflo(uD.z),bfhi(uD.z),bflo(uD.w),bfhi(uD.w)};
    #pragma unroll
    for (int i = 0; i < 8; ++i)
      acc[i] += aA*fA[i] + aB*fB[i] + aC*fC[i] + aD*fD[i];
  }
  for (; t < cnt; ++t){
    int   sA = __shfl(s_l, t, 16);
    float aA = __shfl(a_l, t, 16);
    uint4 u = *(const uint4*)(hp + (sA << 7));
    float fA[8] = {bflo(u.x),bfhi(u.x),bflo(u.y),bfhi(u.y),bflo(u.z),bfhi(u.z),bflo(u.w),bfhi(u.w)};
    #pragma unroll
    for (int i = 0; i < 8; ++i) acc[i] += aA*fA[i];
  }
  for (int jb = start + 16; jb < end; jb += 16){
    int jl2 = jb + ql;
    int s2 = 0; float a2 = 0.f;
    if (jl2 < end){
      s2 = csr[jl2];
      a2 = __expf(lrelu(as_[s2] + adn)) * inv;
    }
    int cnt2 = min(16, end - jb);
    for (int t2 = 0; t2 < cnt2; ++t2){
      int   sA = __shfl(s2, t2, 16);
      float aA = __shfl(a2, t2, 16);
      uint4 u = *(const uint4*)(hp + (sA << 7));
      float fA[8] = {bflo(u.x),bfhi(u.x),bflo(u.y),bfhi(u.y),bflo(u.z),bfhi(u.z),bflo(u.w),bfhi(u.w)};
      #pragma unroll
      for (int i = 0; i < 8; ++i) acc[i] += aA*fA[i];
    }
  }

  if (valid){
    float4 bb0 = *(const float4*)(b2 + c);
    float4 bb1 = *(const float4*)(b2 + c + 4);
    float o[8];
    o[0]=elu_f(acc[0]+bb0.x); o[1]=elu_f(acc[1]+bb0.y);
    o[2]=elu_f(acc[2]+bb0.z); o[3]=elu_f(acc[3]+bb0.w);
    o[4]=elu_f(acc[4]+bb1.x); o[5]=elu_f(acc[5]+bb1.y);
    o[6]=elu_f(acc[6]+bb1.z); o[7]=elu_f(acc[7]+bb1.w);
    uint4 up;
    up.x = packbf(o[0], o[1]); up.y = packbf(o[2], o[3]);
    up.z = packbf(o[4], o[5]); up.w = packbf(o[6], o[7]);
    *(uint4*)(outb + (size_t)n*128 + c) = up;
  }
}

extern "C" void kernel_launch(void* const* d_in, const int* in_sizes, int n_in,
                              void* d_out, int out_size, void* d_ws, size_t ws_size,
                              hipStream_t stream)
{
  (void)n_in; (void)out_size; (void)ws_size;
  const float* x   = (const float*)d_in[0];
  const int*   ei  = (const int*)d_in[1];
  const float* W1  = (const float*)d_in[2];
  const float* a1s = (const float*)d_in[3];
  const float* a1d = (const float*)d_in[4];
  const float* b1  = (const float*)d_in[5];
  const float* W2  = (const float*)d_in[6];
  const float* a2s = (const float*)d_in[7];
  const float* a2d = (const float*)d_in[8];
  const float* b2  = (const float*)d_in[9];
  const float* Wm1 = (const float*)d_in[10];
  const float* bm1 = (const float*)d_in[11];
  const float* Wm2 = (const float*)d_in[12];
  const float* bm2 = (const float*)d_in[13];
  float* out = (float*)d_out;

  const int N = in_sizes[0] / 128;
  const int E = in_sizes[1] / 2;
  const int NB = (N + 63) >> 6;
  const int* srcp = ei;
  const int* dstp = ei + E;

  char* ws = (char*)d_ws;
  unsigned short* xb    = (unsigned short*)ws;
  unsigned short* xa    = (unsigned short*)(ws + (size_t)N*256);
  unsigned short* out1b = (unsigned short*)(ws + (size_t)N*768);
  unsigned short* h2b   = (unsigned short*)(ws + (size_t)N*1280);
  char* tail = ws + (size_t)N*1536;
  unsigned short* BT1a = (unsigned short*)tail;
  unsigned short* BT1b = BT1a + 128*128;
  unsigned short* BT2  = BT1b + 128*128;
  unsigned short* BT3  = BT2 + 128*256;
  float* va   = (float*)(BT3 + 128*128);
  float* as1  = va + 512;
  float* ad1  = as1 + (size_t)2*N;
  float* as2  = ad1 + (size_t)2*N;
  float* ad2  = as2 + N;
  int* bcount = (int*)(ad2 + N);
  int* boff   = bcount + 1024;
  int* gcur   = boff + 1032;
  int* rowptr = gcur + 1024;
  int* csr    = rowptr + N + 1;
  unsigned int* pairs = (unsigned int*)(csr + E + N);

  unsigned short* gb = xb;            // xb dead after agg1x

  const int nbConv = (N*32 + 255)/256;
  const int prepTotal = 128*128 + 128*256 + 128*128 + 512 + 2048;

  // 1: prep
  prep_kernel<<<(prepTotal + 255)/256, 256, 0, stream>>>(
      W1, BT1a, BT1b, W2, BT2, Wm1, BT3, a1s, a1d, va, bcount, gcur, NB);
  // 2: x convert + conv1 alpha dots + edge histogram
  f2bf_hist_kernel<<<nbConv + 64, 256, 0, stream>>>(x, xb, N, va, as1, ad1,
                                                    dstp, E, bcount, NB, nbConv);
  // 3: bucket scatter (scan fused per-block; block 0 publishes boff)
  bscatter_kernel<<<(E + 4095)/4096, 256, 0, stream>>>(srcp, dstp, E, bcount, gcur,
                                                       pairs, boff, NB);
  // 4: per-bucket CSR build
  bbuild_kernel<<<NB, 256, 0, stream>>>(pairs, boff, rowptr, csr, N);

  const int gy   = (N + 127) / 128;
  const int nb16 = (N + 15) / 16;

  // 5-9: main pipeline
  agg1x_kernel<<<nb16, 256, 0, stream>>>(xb, as1, ad1, rowptr, csr, xa, N);
  gemm_conv1_kernel<<<dim3(2, gy), 256, 0, stream>>>(xa, BT1a, BT1b, out1b, N, b1);
  gemm_conv2_kernel<<<dim3(1, gy), 256, 0, stream>>>(out1b, BT2, h2b, N, a2s, a2d, as2, ad2);
  agg2_kernel<<<nb16, 256, 0, stream>>>(h2b, as2, ad2, rowptr, csr, b2, gb, N);
  gemm_mlp_kernel<<<dim3(1, gy), 256, 0, stream>>>(gb, BT3, N, bm1, Wm2, bm2, out);
}